// Round 21
// baseline (71.027 us; speedup 1.0000x reference)
//
#include <hip/hip_runtime.h>
#include <math.h>

#define N_BINS 229
#define MODEL  128
#define OUTD   88
#define WSZ    30
#define WLEN   61
#define BB     4
#define TT     2048
#define CTANH  2.8853900817779268f   // 2*log2(e)

#define KPAD   256                   // padded K (229 -> 256 = 8 x 32)
#define NPAD   384                   // padded N (H 128 | E 128 | S1 88 | pad)
#define NTILES 22                    // ceil(344/16)
#define ROWS_F 8
#define FHALO  71
#define EPADU  68                    // u32 stride per E halo row
#define APREP_BLKS 2048              // 8192*256/(256*4)

typedef __attribute__((ext_vector_type(8))) short  short8v;  // 8 bf16 (4 VGPR)
typedef __attribute__((ext_vector_type(4))) float  f32x4;

__device__ __forceinline__ unsigned short bf16_rne(float x) {
    unsigned int u = __float_as_uint(x);
    return (unsigned short)((u + 0x7FFFu + ((u >> 16) & 1u)) >> 16);
}
__device__ __forceinline__ float sigmoidf_(float x) {
    return __builtin_amdgcn_rcpf(1.0f + __expf(-x));
}

// ---- Prep (split grid): blocks [0,2048) convert spec -> Ahi/Alo bf16
// (hi/lo split: A-side rounding cancels in 2-MFMA scheme); blocks
// [2048, 2048+384) build Wt[n][k] = bf16 of (W_h*C | W_e*C | W1)^T.
__global__ __launch_bounds__(256) void k_prep(
        const float* __restrict__ spec,
        const float* __restrict__ W_h, const float* __restrict__ W_e,
        const float* __restrict__ W1,
        unsigned short* __restrict__ Ahi, unsigned short* __restrict__ Alo,
        unsigned short* __restrict__ Wt) {
    if (blockIdx.x < APREP_BLKS) {
        const int idx = (blockIdx.x * 256 + threadIdx.x) * 4;  // elem in [8192][256]
        const int m = idx >> 8, k = idx & 255;
        const float* __restrict__ sp = spec + (size_t)m * N_BINS;
        unsigned int hi0 = 0, hi1 = 0, lo0 = 0, lo1 = 0;
#pragma unroll
        for (int j = 0; j < 4; ++j) {
            const float v = (k + j < N_BINS) ? sp[k + j] : 0.0f;
            const unsigned short h = bf16_rne(v);
            const float rr = v - __uint_as_float((unsigned int)h << 16);
            const unsigned short l = bf16_rne(rr);
            if (j < 2) { hi0 |= (unsigned int)h << (16 * j);
                         lo0 |= (unsigned int)l << (16 * j); }
            else       { hi1 |= (unsigned int)h << (16 * (j - 2));
                         lo1 |= (unsigned int)l << (16 * (j - 2)); }
        }
        *(uint2*)(Ahi + idx) = make_uint2(hi0, hi1);   // 8B aligned
        *(uint2*)(Alo + idx) = make_uint2(lo0, lo1);
    } else {
        const int n = blockIdx.x - APREP_BLKS;   // 0..383
        const int k = threadIdx.x;               // 0..255
        float v = 0.0f;
        if (k < N_BINS) {
            if (n < 128)      v = W_h[k * MODEL + n] * CTANH;
            else if (n < 256) v = W_e[k * MODEL + (n - 128)] * CTANH;
            else if (n < 344) v = W1[k * OUTD + (n - 256)];
        }
        Wt[n * KPAD + k] = bf16_rne(v);
    }
}

// ---- Pass 1 (MFMA GEMM v4): pre-converted A, pure load+MFMA inner loop ----
// grid = 512 m-tiles x 3 parts, 8 waves/block, wave = one 16-col n-tile.
// Per kb: 3 x 16B aligned loads + 2 MFMA (hi/lo). Zero conversion VALU.
// D layout (verified): D[(lane>>4)*4 + r][lane&15].
__global__ __launch_bounds__(512, 4) void k_he_mfma(
        const unsigned short* __restrict__ Ahi,
        const unsigned short* __restrict__ Alo,
        const unsigned short* __restrict__ Wt,
        const float* __restrict__ b_attn,
        float* __restrict__ H,
        unsigned int* __restrict__ Ebf,
        unsigned int* __restrict__ S1b) {
    const int tid  = threadIdx.x;
    const int lane = tid & 63;
    const int wv   = tid >> 6;           // 0..7
    const int mt   = blockIdx.x / 3;
    const int part = blockIdx.x - mt * 3;
    const int tile = part * 8 + wv;      // 0..23
    if (tile >= NTILES) return;          // no barriers in kernel -> legal
    const int gm0   = mt * 16;
    const int n0    = tile * 16;
    const int mfrag = lane & 15;
    const int kg    = lane >> 4;         // 0..3

    f32x4 acc = {0, 0, 0, 0};
    const unsigned short* __restrict__ ah_p = Ahi + (size_t)(gm0 + mfrag) * KPAD;
    const unsigned short* __restrict__ al_p = Alo + (size_t)(gm0 + mfrag) * KPAD;
    const unsigned short* __restrict__ Bp   = Wt + (size_t)(n0 + mfrag) * KPAD;

#pragma unroll
    for (int kb = 0; kb < 8; ++kb) {
        const int k0 = kb * 32 + kg * 8;
        const short8v ah = *(const short8v*)(ah_p + k0);   // 16B aligned
        const short8v al = *(const short8v*)(al_p + k0);
        const short8v bb = *(const short8v*)(Bp + k0);
        acc = __builtin_amdgcn_mfma_f32_16x16x32_bf16(ah, bb, acc, 0, 0, 0);
        acc = __builtin_amdgcn_mfma_f32_16x16x32_bf16(al, bb, acc, 0, 0, 0);
    }

    // ---- epilogue: route tile to H / Ebf / S1b (tile-uniform region) ----
    const int gn = n0 + mfrag;
    if (gn < 128) {
        const float bc = b_attn[gn] * CTANH;
#pragma unroll
        for (int r = 0; r < 4; ++r) {
            const int gm = gm0 + (kg << 2) + r;
            H[(size_t)gm * MODEL + gn] = acc[r] + bc;
        }
    } else if (gn < 256) {
        const int ne = gn - 128;
#pragma unroll
        for (int r = 0; r < 4; ++r) {
            const float own = acc[r];
            const float pv  = __shfl_xor(own, 1, 64);
            if ((ne & 1) == 0) {
                const int gm = gm0 + (kg << 2) + r;
                Ebf[(size_t)gm * 64 + (ne >> 1)] =
                    (unsigned int)bf16_rne(own) |
                    ((unsigned int)bf16_rne(pv) << 16);
            }
        }
    } else if (gn < 344) {
        const int ns = gn - 256;
#pragma unroll
        for (int r = 0; r < 4; ++r) {
            const float own = acc[r];
            const float pv  = __shfl_xor(own, 1, 64);
            if ((ns & 1) == 0) {
                const int gm = gm0 + (kg << 2) + r;
                S1b[(size_t)gm * 44 + (ns >> 1)] =
                    (unsigned int)bf16_rne(own) |
                    ((unsigned int)bf16_rne(pv) << 16);
            }
        }
    }
}

// ---- Pass 2 (fused, r20-exact single barrier): stage E+S1+H+V -> barrier ->
// scores -> softmax -> pooling (all wave-local). LDS 38.5 KB -> 4 blocks/CU.
__global__ __launch_bounds__(512, 4) void k_fused(
        const float* __restrict__ H,
        const unsigned int* __restrict__ Ebf,
        const float* __restrict__ v_w,
        const unsigned int* __restrict__ S1b,
        const float* __restrict__ b1,
        float* __restrict__ pred,
        float* __restrict__ a_out) {
    const int nb   = blockIdx.x;
    const int tid  = threadIdx.x;
    const int wv   = tid >> 6;              // 0..7 = local row
    const int lane = tid & 63;
    const int r0   = nb * ROWS_F;
    const int b    = r0 >> 11;              // T = 2048
    const int t0   = r0 & (TT - 1);
    const int r    = r0 + wv;
    const int t    = t0 + wv;

    __shared__ unsigned int Ebs[FHALO * EPADU];     // 19312 B
    __shared__ unsigned int S1u[FHALO * 44];        // 12496 B
    __shared__ float4 Hs4[ROWS_F * 32];             //  4096 B
    __shared__ float4 Vs4[32];                      //   512 B
    __shared__ float  scA[ROWS_F][64];              //  2048 B (scores, then aEff)

    const uint4* __restrict__ Eb16 = (const uint4*)Ebf + (size_t)b * TT * 16;
    for (int i = tid; i < FHALO * 16; i += 512) {
        const int row = i >> 4, c = i & 15;
        const int s   = t0 - WSZ + row;
        uint4 v = make_uint4(0u, 0u, 0u, 0u);
        if (s >= 0 && s < TT) v = Eb16[(size_t)s * 16 + c];
        *(uint4*)&Ebs[row * EPADU + (c << 2)] = v;
    }
    const uint4* __restrict__ Sb4 = (const uint4*)S1b + (size_t)b * TT * 11;
    for (int i = tid; i < FHALO * 11; i += 512) {
        const int row = i / 11, c = i - row * 11;
        const int s   = t0 - WSZ + row;
        uint4 v = make_uint4(0u, 0u, 0u, 0u);
        if (s >= 0 && s < TT) v = Sb4[(size_t)s * 11 + c];
        *(uint4*)&S1u[row * 44 + (c << 2)] = v;
    }
    if (tid < ROWS_F * 32)
        Hs4[tid] = ((const float4*)H)[(size_t)r0 * 32 + tid];
    else if (tid < ROWS_F * 32 + 32)
        Vs4[tid - ROWS_F * 32] = ((const float4*)v_w)[tid - ROWS_F * 32];
    __syncthreads();                        // the ONLY barrier

    const int g  = lane & 3;
    const int w0 = lane >> 2;

    float vs = 0.f;
#pragma unroll
    for (int q = 0; q < 8; ++q) {
        const float4 vq = Vs4[(q << 2) + g];
        vs += (vq.x + vq.y) + (vq.z + vq.w);
    }
    vs += __shfl_xor(vs, 1, 64);
    vs += __shfl_xor(vs, 2, 64);

    int ro[4];
#pragma unroll
    for (int it = 0; it < 4; ++it)
        ro[it] = (wv + w0 + it * 16) * EPADU;       // hi in [0,70]

    const float4* __restrict__ HsR = &Hs4[wv * 32];

    float pp[4] = {0.f, 0.f, 0.f, 0.f};
#pragma unroll
    for (int q = 0; q < 8; ++q) {
        const int    cq = (q << 2) + g;
        const float4 hq = HsR[cq];          // pre-scaled by CTANH
        const float4 vq = Vs4[cq];
        const float nx = -2.f * vq.x, ny = -2.f * vq.y,
                    nz = -2.f * vq.z, nw = -2.f * vq.w;
#pragma unroll
        for (int it = 0; it < 4; ++it) {
            const uint2 e2 = *(const uint2*)&Ebs[ro[it] + (cq << 1)];
            const float f0 = __uint_as_float(e2.x << 16);
            const float f1 = __uint_as_float(e2.x & 0xFFFF0000u);
            const float f2 = __uint_as_float(e2.y << 16);
            const float f3 = __uint_as_float(e2.y & 0xFFFF0000u);
            float u;
            u = __builtin_amdgcn_rcpf(__builtin_amdgcn_exp2f(f0 + hq.x) + 1.f);
            pp[it] = fmaf(nx, u, pp[it]);
            u = __builtin_amdgcn_rcpf(__builtin_amdgcn_exp2f(f1 + hq.y) + 1.f);
            pp[it] = fmaf(ny, u, pp[it]);
            u = __builtin_amdgcn_rcpf(__builtin_amdgcn_exp2f(f2 + hq.z) + 1.f);
            pp[it] = fmaf(nz, u, pp[it]);
            u = __builtin_amdgcn_rcpf(__builtin_amdgcn_exp2f(f3 + hq.w) + 1.f);
            pp[it] = fmaf(nw, u, pp[it]);
        }
    }
#pragma unroll
    for (int it = 0; it < 4; ++it) {
        float p = pp[it];
        p += __shfl_xor(p, 1, 64);
        p += __shfl_xor(p, 2, 64);
        const int w = w0 + it * 16;
        if (g == 0 && w < WLEN) scA[wv][w] = p + vs;
    }

    {
        float x = (lane < WLEN) ? scA[wv][lane] : -INFINITY;
        float mx = x;
#pragma unroll
        for (int d = 32; d >= 1; d >>= 1) mx = fmaxf(mx, __shfl_xor(mx, d, 64));
        float e = (lane < WLEN) ? __expf(x - mx) : 0.0f;
        float sm = e;
#pragma unroll
        for (int d = 32; d >= 1; d >>= 1) sm += __shfl_xor(sm, d, 64);
        const float a = e * __builtin_amdgcn_rcpf(sm);
        if (lane < WLEN) a_out[(size_t)r * WLEN + lane] = a;
        const int sl = t + lane - WSZ;
        scA[wv][lane] = (lane < WLEN && sl >= 0 && sl < TT) ? a : 0.0f;
    }

    if (lane < 44) {
        float a1 = 0.f, a2 = 0.f;
#pragma unroll 4
        for (int w = 0; w < 64; ++w) {
            const float at = scA[wv][w];                // LDS broadcast
            const unsigned int pv = S1u[(wv + w) * 44 + lane];
            a1 = fmaf(at, __uint_as_float(pv << 16),         a1);
            a2 = fmaf(at, __uint_as_float(pv & 0xFFFF0000u), a2);
        }
        const int o = lane << 1;
        pred[(size_t)r * OUTD + o]     = sigmoidf_(a1 + b1[o]);
        pred[(size_t)r * OUTD + o + 1] = sigmoidf_(a2 + b1[o + 1]);
    }
}

extern "C" void kernel_launch(void* const* d_in, const int* in_sizes, int n_in,
                              void* d_out, int out_size, void* d_ws, size_t ws_size,
                              hipStream_t stream) {
    const float* spec   = (const float*)d_in[0];
    const float* W_h    = (const float*)d_in[1];
    const float* W_e    = (const float*)d_in[2];
    const float* b_attn = (const float*)d_in[3];
    const float* v_w    = (const float*)d_in[4];
    const float* W1     = (const float*)d_in[5];
    const float* b1     = (const float*)d_in[6];

    const int n_rows = BB * TT;                       // 8192
    char* ws = (char*)d_ws;                           // ws_size ~= 256 MB
    float*          H   = (float*)ws;                                // 4 MB
    unsigned int*   Ebf = (unsigned int*)(ws + ((size_t)4  << 20));  // 2 MB
    unsigned int*   S1b = (unsigned int*)(ws + ((size_t)6  << 20));  // 1.44 MB
    unsigned short* Wt  = (unsigned short*)(ws + ((size_t)8 << 20)); // 192 KB
    unsigned short* Ahi = (unsigned short*)(ws + ((size_t)9 << 20)); // 4 MB
    unsigned short* Alo = (unsigned short*)(ws + ((size_t)13 << 20));// 4 MB

    float* pred  = (float*)d_out;                     // 8192*88
    float* a_out = pred + (size_t)n_rows * OUTD;      // 8192*61

    k_prep   <<<APREP_BLKS + NPAD, 256, 0, stream>>>(spec, W_h, W_e, W1,
                                                     Ahi, Alo, Wt);
    k_he_mfma<<<(n_rows / 16) * 3, 512, 0, stream>>>(Ahi, Alo, Wt, b_attn,
                                                     H, Ebf, S1b);
    k_fused  <<<n_rows / ROWS_F,   512, 0, stream>>>(H, Ebf, v_w, S1b, b1,
                                                     pred, a_out);
}

// Round 22
// 53.475 us; speedup vs baseline: 1.3282x; 1.3282x over previous
//
#include <hip/hip_runtime.h>
#include <math.h>

#define N_BINS 229
#define MODEL  128
#define OUTD   88
#define WSZ    30
#define WLEN   61
#define BB     4
#define TT     2048
#define CTANH  2.8853900817779268f   // 2*log2(e)

#define KPAD   256                   // padded K (229 -> 256 = 8 x 32)
#define NPAD   384                   // padded N (H 128 | E 128 | S1 88 | pad)
#define BSTRB  80                    // LDS row stride bytes (40 bf16, 16B-mult)
#define ROWS_F 8
#define FHALO  71
#define EPADU  68

typedef __attribute__((ext_vector_type(8))) short  short8v;  // 8 bf16 (4 VGPR)
typedef __attribute__((ext_vector_type(4))) float  f32x4;

__device__ __forceinline__ unsigned short bf16_rne(float x) {
    unsigned int u = __float_as_uint(x);
    return (unsigned short)((u + 0x7FFFu + ((u >> 16) & 1u)) >> 16);
}
__device__ __forceinline__ float sigmoidf_(float x) {
    return __builtin_amdgcn_rcpf(1.0f + __expf(-x));
}

// ---- Prep: Wt[n][k] = bf16 of (W_h*C | W_e*C | W1)^T, zero-padded ----
__global__ __launch_bounds__(256) void k_prep_w(
        const float* __restrict__ W_h, const float* __restrict__ W_e,
        const float* __restrict__ W1, unsigned short* __restrict__ Wt) {
    const int n = blockIdx.x;        // 0..383
    const int k = threadIdx.x;       // 0..255
    float v = 0.0f;
    if (k < N_BINS) {
        if (n < 128)      v = W_h[k * MODEL + n] * CTANH;
        else if (n < 256) v = W_e[k * MODEL + (n - 128)] * CTANH;
        else if (n < 344) v = W1[k * OUTD + (n - 256)];
    }
    Wt[n * KPAD + k] = bf16_rne(v);
}

// ---- Pass 1 (MFMA GEMM): [8192 x 229] @ [229 x 344] -> H, Ebf, S1 ----
// BM=16, full N per block (24 tiles of 16, 8 waves x 3 tiles). A (spec) is
// converted fp32->bf16 hi+lo in-kernel (2 MFMA/tile: removes A-side rounding).
// D layout (verified): D[(lane>>4)*4 + r][lane&15].
__global__ __launch_bounds__(512, 4) void k_he_mfma(
        const float* __restrict__ spec,
        const unsigned short* __restrict__ Wt,
        const float* __restrict__ b_attn,
        float* __restrict__ H,
        unsigned int* __restrict__ Ebf,
        float* __restrict__ S1) {
    __shared__ __align__(16) unsigned char lds[NPAD * BSTRB + 2 * 16 * BSTRB];
    unsigned char* Bl  = lds;                         // [384][80B]
    unsigned char* Ahi = lds + NPAD * BSTRB;          // [16][80B]
    unsigned char* Alo = Ahi + 16 * BSTRB;            // [16][80B]

    const int tid   = threadIdx.x;
    const int gm0   = blockIdx.x * 16;
    const int lane  = tid & 63;
    const int wv    = tid >> 6;          // 0..7
    const int mfrag = lane & 15;
    const int kg    = lane >> 4;         // 0..3

    f32x4 acc0 = {0,0,0,0}, acc1 = {0,0,0,0}, acc2 = {0,0,0,0};
    const uint4* __restrict__ Wt4 = (const uint4*)Wt;

    for (int kb = 0; kb < 8; ++kb) {
        __syncthreads();                 // protect LDS from previous reads
        // ---- stage B K-slice: 384 rows x 64 B (1536 x 16B units) ----
#pragma unroll
        for (int it = 0; it < 3; ++it) {
            const int u = it * 512 + tid;
            const int row = u >> 2, q = u & 3;
            const uint4 v = Wt4[row * 32 + kb * 4 + q];
            *(uint4*)(Bl + row * BSTRB + q * 16) = v;
        }
        // ---- stage A tile: 16 rows x 32 k, fp32 -> bf16 hi+lo ----
        if (tid < 256) {
            const int row = tid >> 4, kp = tid & 15;
            const int gk  = kb * 32 + kp * 2;
            const float* __restrict__ sp = spec + (size_t)(gm0 + row) * N_BINS;
            const float v0 = (gk     < N_BINS) ? sp[gk]     : 0.0f;
            const float v1 = (gk + 1 < N_BINS) ? sp[gk + 1] : 0.0f;
            const unsigned short h0 = bf16_rne(v0), h1 = bf16_rne(v1);
            const float r0 = v0 - __uint_as_float((unsigned int)h0 << 16);
            const float r1 = v1 - __uint_as_float((unsigned int)h1 << 16);
            *(unsigned int*)(Ahi + row * BSTRB + kp * 4) =
                (unsigned int)h0 | ((unsigned int)h1 << 16);
            *(unsigned int*)(Alo + row * BSTRB + kp * 4) =
                (unsigned int)bf16_rne(r0) | ((unsigned int)bf16_rne(r1) << 16);
        }
        __syncthreads();

        const short8v ah = *(const short8v*)(Ahi + mfrag * BSTRB + kg * 16);
        const short8v al = *(const short8v*)(Alo + mfrag * BSTRB + kg * 16);
        const int n0 = wv * 48;
        const short8v b0 = *(const short8v*)(Bl + (n0      + mfrag) * BSTRB + kg * 16);
        const short8v b1 = *(const short8v*)(Bl + (n0 + 16 + mfrag) * BSTRB + kg * 16);
        const short8v b2 = *(const short8v*)(Bl + (n0 + 32 + mfrag) * BSTRB + kg * 16);
        acc0 = __builtin_amdgcn_mfma_f32_16x16x32_bf16(ah, b0, acc0, 0, 0, 0);
        acc0 = __builtin_amdgcn_mfma_f32_16x16x32_bf16(al, b0, acc0, 0, 0, 0);
        acc1 = __builtin_amdgcn_mfma_f32_16x16x32_bf16(ah, b1, acc1, 0, 0, 0);
        acc1 = __builtin_amdgcn_mfma_f32_16x16x32_bf16(al, b1, acc1, 0, 0, 0);
        acc2 = __builtin_amdgcn_mfma_f32_16x16x32_bf16(ah, b2, acc2, 0, 0, 0);
        acc2 = __builtin_amdgcn_mfma_f32_16x16x32_bf16(al, b2, acc2, 0, 0, 0);
    }

    // ---- epilogue: route tiles to H / Ebf / S1 ----
#pragma unroll
    for (int t = 0; t < 3; ++t) {
        const f32x4 acc = (t == 0) ? acc0 : (t == 1) ? acc1 : acc2;
        const int gn = wv * 48 + t * 16 + mfrag;     // region uniform per tile
        if (gn < 128) {
            const float bc = b_attn[gn] * CTANH;
#pragma unroll
            for (int r = 0; r < 4; ++r) {
                const int gm = gm0 + (kg << 2) + r;
                H[(size_t)gm * MODEL + gn] = acc[r] + bc;
            }
        } else if (gn < 256) {
            const int ne = gn - 128;
#pragma unroll
            for (int r = 0; r < 4; ++r) {
                const float own = acc[r];
                const float pv  = __shfl_xor(own, 1, 64);
                if ((ne & 1) == 0) {
                    const int gm = gm0 + (kg << 2) + r;
                    Ebf[(size_t)gm * 64 + (ne >> 1)] =
                        (unsigned int)bf16_rne(own) |
                        ((unsigned int)bf16_rne(pv) << 16);
                }
            }
        } else if (gn < 344) {
            const int ns = gn - 256;
#pragma unroll
            for (int r = 0; r < 4; ++r) {
                const int gm = gm0 + (kg << 2) + r;
                S1[(size_t)gm * OUTD + ns] = acc[r];
            }
        }
    }
}

// ---- Pass 2 (fused): scores + softmax + 88-dim pooling + sigmoid ----
__global__ __launch_bounds__(512, 4) void k_fused(
        const float* __restrict__ H,
        const unsigned int* __restrict__ Ebf,
        const float* __restrict__ v_w,
        const float* __restrict__ S1,
        const float* __restrict__ b1,
        float* __restrict__ pred,
        float* __restrict__ a_out) {
    const int nb   = blockIdx.x;
    const int tid  = threadIdx.x;
    const int wv   = tid >> 6;              // 0..7 = local row
    const int lane = tid & 63;
    const int r0   = nb * ROWS_F;
    const int b    = r0 >> 11;              // T = 2048
    const int t0   = r0 & (TT - 1);
    const int r    = r0 + wv;
    const int t    = t0 + wv;

    __shared__ __align__(16) unsigned char ubuf[FHALO * OUTD * 4];  // 24992 B
    unsigned int* Ebs = (unsigned int*)ubuf;        // [FHALO][EPADU]
    float*        S1h = (float*)ubuf;               // [FHALO][88]
    __shared__ float4 Hs4[ROWS_F * 32];             //  4096 B
    __shared__ float4 Vs4[32];                      //   512 B
    __shared__ float  scA[ROWS_F][64];              //  2048 B
    __shared__ float  cf[ROWS_F][64];               //  2048 B

    const uint4* __restrict__ Eb16 = (const uint4*)Ebf + (size_t)b * TT * 16;
    for (int i = tid; i < FHALO * 16; i += 512) {
        const int row = i >> 4, c = i & 15;
        const int s   = t0 - WSZ + row;
        uint4 v = make_uint4(0u, 0u, 0u, 0u);
        if (s >= 0 && s < TT) v = Eb16[(size_t)s * 16 + c];
        *(uint4*)&Ebs[row * EPADU + (c << 2)] = v;
    }
    if (tid < ROWS_F * 32)
        Hs4[tid] = ((const float4*)H)[(size_t)r0 * 32 + tid];
    else if (tid < ROWS_F * 32 + 32)
        Vs4[tid - ROWS_F * 32] = ((const float4*)v_w)[tid - ROWS_F * 32];
    __syncthreads();

    const int g  = lane & 3;
    const int w0 = lane >> 2;

    float vs = 0.f;
#pragma unroll
    for (int q = 0; q < 8; ++q) {
        const float4 vq = Vs4[(q << 2) + g];
        vs += (vq.x + vq.y) + (vq.z + vq.w);
    }
    vs += __shfl_xor(vs, 1, 64);
    vs += __shfl_xor(vs, 2, 64);

    int ro[4];
#pragma unroll
    for (int it = 0; it < 4; ++it)
        ro[it] = (wv + w0 + it * 16) * EPADU;

    const float4* __restrict__ HsR = &Hs4[wv * 32];

    float pp[4] = {0.f, 0.f, 0.f, 0.f};
#pragma unroll
    for (int q = 0; q < 8; ++q) {
        const int    cq = (q << 2) + g;
        const float4 hq = HsR[cq];
        const float4 vq = Vs4[cq];
        const float nx = -2.f * vq.x, ny = -2.f * vq.y,
                    nz = -2.f * vq.z, nw = -2.f * vq.w;
#pragma unroll
        for (int it = 0; it < 4; ++it) {
            const uint2 e2 = *(const uint2*)&Ebs[ro[it] + (cq << 1)];
            const float f0 = __uint_as_float(e2.x << 16);
            const float f1 = __uint_as_float(e2.x & 0xFFFF0000u);
            const float f2 = __uint_as_float(e2.y << 16);
            const float f3 = __uint_as_float(e2.y & 0xFFFF0000u);
            float u;
            u = __builtin_amdgcn_rcpf(__builtin_amdgcn_exp2f(f0 + hq.x) + 1.f);
            pp[it] = fmaf(nx, u, pp[it]);
            u = __builtin_amdgcn_rcpf(__builtin_amdgcn_exp2f(f1 + hq.y) + 1.f);
            pp[it] = fmaf(ny, u, pp[it]);
            u = __builtin_amdgcn_rcpf(__builtin_amdgcn_exp2f(f2 + hq.z) + 1.f);
            pp[it] = fmaf(nz, u, pp[it]);
            u = __builtin_amdgcn_rcpf(__builtin_amdgcn_exp2f(f3 + hq.w) + 1.f);
            pp[it] = fmaf(nw, u, pp[it]);
        }
    }
#pragma unroll
    for (int it = 0; it < 4; ++it) {
        float p = pp[it];
        p += __shfl_xor(p, 1, 64);
        p += __shfl_xor(p, 2, 64);
        const int w = w0 + it * 16;
        if (g == 0 && w < WLEN) scA[wv][w] = p + vs;
    }

    {
        float x = (lane < WLEN) ? scA[wv][lane] : -INFINITY;
        float mx = x;
#pragma unroll
        for (int d = 32; d >= 1; d >>= 1) mx = fmaxf(mx, __shfl_xor(mx, d, 64));
        float e = (lane < WLEN) ? __expf(x - mx) : 0.0f;
        float sm = e;
#pragma unroll
        for (int d = 32; d >= 1; d >>= 1) sm += __shfl_xor(sm, d, 64);
        const float a = e * __builtin_amdgcn_rcpf(sm);
        if (lane < WLEN) a_out[(size_t)r * WLEN + lane] = a;
        const int sl = t + lane - WSZ;
        cf[wv][lane] = (lane < WLEN && sl >= 0 && sl < TT) ? a : 0.0f;
    }

    __syncthreads();

    const float4* __restrict__ Sb4 = (const float4*)S1 + (size_t)b * TT * 22;
    for (int i = tid; i < FHALO * 22; i += 512) {
        const int row = i / 22, c = i - row * 22;
        const int s   = t0 - WSZ + row;
        float4 v = make_float4(0.f, 0.f, 0.f, 0.f);
        if (s >= 0 && s < TT) v = Sb4[(size_t)s * 22 + c];
        *(float4*)&S1h[row * OUTD + (c << 2)] = v;
    }
    __syncthreads();

    const int o2 = 64 + (lane < 24 ? lane : 23);
    float a1 = 0.f, a2 = 0.f;
#pragma unroll 4
    for (int w = 0; w < 64; ++w) {
        const float at = cf[wv][w];
        const float* __restrict__ rowp = &S1h[(wv + w) * OUTD];
        a1 = fmaf(at, rowp[lane], a1);
        a2 = fmaf(at, rowp[o2],   a2);
    }
    pred[(size_t)r * OUTD + lane] = sigmoidf_(a1 + b1[lane]);
    if (lane < 24)
        pred[(size_t)r * OUTD + 64 + lane] = sigmoidf_(a2 + b1[64 + lane]);
}

extern "C" void kernel_launch(void* const* d_in, const int* in_sizes, int n_in,
                              void* d_out, int out_size, void* d_ws, size_t ws_size,
                              hipStream_t stream) {
    const float* spec   = (const float*)d_in[0];
    const float* W_h    = (const float*)d_in[1];
    const float* W_e    = (const float*)d_in[2];
    const float* b_attn = (const float*)d_in[3];
    const float* v_w    = (const float*)d_in[4];
    const float* W1     = (const float*)d_in[5];
    const float* b1     = (const float*)d_in[6];

    const int n_rows = BB * TT;                       // 8192
    char* ws = (char*)d_ws;
    float*          H   = (float*)ws;                               // 4 MB
    unsigned int*   Ebf = (unsigned int*)(ws + ((size_t)4 << 20));  // 2 MB
    float*          S1  = (float*)(ws + ((size_t)6 << 20));         // 2.875 MB
    unsigned short* Wt  = (unsigned short*)(ws + ((size_t)9 << 20)); // 192 KB

    float* pred  = (float*)d_out;                     // 8192*88
    float* a_out = pred + (size_t)n_rows * OUTD;      // 8192*61

    k_prep_w <<<NPAD,         256, 0, stream>>>(W_h, W_e, W1, Wt);
    k_he_mfma<<<n_rows / 16,  512, 0, stream>>>(spec, Wt, b_attn, H, Ebf, S1);
    k_fused  <<<n_rows / ROWS_F, 512, 0, stream>>>(H, Ebf, v_w, S1, b1,
                                                   pred, a_out);
}